// Round 6
// baseline (361.354 us; speedup 1.0000x reference)
//
#include <hip/hip_runtime.h>
#include <hip/hip_bf16.h>

// Tucker: out[a,s,t] = sum_{f,e,g} act[a,f]*state[s,e]*core[f,e,g]*state[t,g]
// A=64, S=T=1024, E=G=64, F=32.
// prep:   state->bf16 (sb) and Wt[a][g][e]=sum_f act*core (bf16)
// gemm_u: U[a][s][g] = state(s,e) . W_a(g,e)^T          (MFMA, bf16, 8 MB)
// gemm_out: out[(a,s)][t] = U . state(t,g)^T            (MFMA, fp32, 256 MiB)
//
// R5 = MEASUREMENT ROUND. Four write-side theories (store width, NT/duty,
// line-completion, contiguity) all failed; gemm_out has never been directly
// observed (harness poison-fills monopolize the top-5 table). This round runs
// R3's exact pipeline but gemm_out repeats its work 4x internally (idempotent,
// deterministic) so its dispatch exceeds the ~160us fills and surfaces in the
// counter table with dur/WRITE/FETCH/MfmaUtil/Occupancy.
//   O = dispatch_dur/4, cross-checked vs (total - 127.2)/3.

typedef __attribute__((ext_vector_type(8))) __bf16 bf16x8;
typedef __attribute__((ext_vector_type(4))) float f32x4;

static __device__ __forceinline__ unsigned short f2bf(float x) {
    union { float f; unsigned int u; } c; c.f = x;
    unsigned int lsb = (c.u >> 16) & 1u;
    c.u += 0x7fffu + lsb;               // round-to-nearest-even
    return (unsigned short)(c.u >> 16);
}

// ---- prep: fused state->bf16 conversion + Wt build (IDENTICAL to R3) ----
__global__ void prep(const float* __restrict__ state, const float* __restrict__ act,
                     const float* __restrict__ core,
                     unsigned short* __restrict__ sb, unsigned short* __restrict__ wt) {
    int a = blockIdx.x;           // 64 blocks
    int t = threadIdx.x;          // 256 threads
    {   // state cvt: 16384 float4s, 256 per block
        int i = a * 256 + t;
        float4 v = reinterpret_cast<const float4*>(state)[i];
        union { unsigned short u[4]; unsigned long long ull; } r;
        r.u[0] = f2bf(v.x); r.u[1] = f2bf(v.y); r.u[2] = f2bf(v.z); r.u[3] = f2bf(v.w);
        reinterpret_cast<unsigned long long*>(sb)[i] = r.ull;
    }
    __shared__ float af[32];
    if (t < 32) af[t] = act[a * 32 + t];
    __syncthreads();
    for (int i = 0; i < 16; ++i) {
        int idx = t + i * 256;    // 4096 (e,g) pairs
        int e = idx >> 6, g = idx & 63;
        float acc = 0.f;
#pragma unroll
        for (int f = 0; f < 32; ++f)
            acc += af[f] * core[(f * 64 + e) * 64 + g];
        wt[a * 4096 + g * 64 + e] = f2bf(acc);   // store transposed (g,e)
    }
}

// ---- gemm_u (IDENTICAL to R3) ----
__global__ __launch_bounds__(256) void gemm_u(const unsigned short* __restrict__ sb,
                                              const unsigned short* __restrict__ wt,
                                              unsigned short* __restrict__ u) {
    int bx = blockIdx.x;                  // 256 blocks: a(64) x stile(4)
    int a = bx >> 2, st = bx & 3;
    int wid = threadIdx.x >> 6, lane = threadIdx.x & 63;
    int s0 = st * 256 + wid * 64;
    int lr = lane & 15, lk = (lane >> 4) * 8;
    int rr = (lane >> 4) * 4;
    const unsigned short* wta = wt + a * 4096;

    f32x4 acc[4][4] = {};                 // acc[mg][ns]
    bf16x8 afr[4][2], bfr[4][2];
#pragma unroll
    for (int mg = 0; mg < 4; ++mg)
#pragma unroll
        for (int kk = 0; kk < 2; ++kk)
            afr[mg][kk] = *reinterpret_cast<const bf16x8*>(wta + (mg * 16 + lr) * 64 + kk * 32 + lk);
#pragma unroll
    for (int ns = 0; ns < 4; ++ns)
#pragma unroll
        for (int kk = 0; kk < 2; ++kk)
            bfr[ns][kk] = *reinterpret_cast<const bf16x8*>(sb + (s0 + ns * 16 + lr) * 64 + kk * 32 + lk);
#pragma unroll
    for (int kk = 0; kk < 2; ++kk)
#pragma unroll
        for (int mg = 0; mg < 4; ++mg)
#pragma unroll
            for (int ns = 0; ns < 4; ++ns)
                acc[mg][ns] = __builtin_amdgcn_mfma_f32_16x16x32_bf16(afr[mg][kk], bfr[ns][kk], acc[mg][ns], 0, 0, 0);

#pragma unroll
    for (int ns = 0; ns < 4; ++ns) {
        int srow = s0 + ns * 16 + lr;
        unsigned short* urow = u + (size_t)a * 65536 + (size_t)srow * 64;
#pragma unroll
        for (int mg = 0; mg < 4; ++mg) {
            union { unsigned short h[4]; unsigned long long ull; } pk;
#pragma unroll
            for (int q = 0; q < 4; ++q) pk.h[q] = f2bf(acc[mg][ns][q]);
            *reinterpret_cast<unsigned long long*>(urow + mg * 16 + rr) = pk.ull;
        }
    }
}

// ---- gemm_out: R3 structure, x4 internal repetition for measurement ----
__global__ __launch_bounds__(256) void gemm_out(const unsigned short* __restrict__ u,
                                                const unsigned short* __restrict__ sb,
                                                float* __restrict__ out) {
    int bx = blockIdx.x;                  // 1024 blocks
    int xcd = bx & 7;
    int idx = bx >> 3;                    // 0..127
    int rb = xcd * 128 + idx;
    int wid = threadIdx.x >> 6, lane = threadIdx.x & 63;
    int R0 = rb * 64 + wid * 16;          // 16 out-rows per wave
    int lr = lane & 15, lk = (lane >> 4) * 8;
    int rr = (lane >> 4) * 4;

    // u rows for this wave (read once)
    bf16x8 b0 = *reinterpret_cast<const bf16x8*>(u + (size_t)(R0 + lr) * 64 + lk);
    bf16x8 b1 = *reinterpret_cast<const bf16x8*>(u + (size_t)(R0 + lr) * 64 + 32 + lk);

    float* orow = out + (size_t)(R0 + lr) * 1024 + rr;

    for (int rep = 0; rep < 4; ++rep) {
        asm volatile("" ::: "memory");    // keep reps distinct (no hoist/merge)
        bf16x8 a0 = *reinterpret_cast<const bf16x8*>(sb + lr * 64 + lk);
        bf16x8 a1 = *reinterpret_cast<const bf16x8*>(sb + lr * 64 + 32 + lk);
#pragma unroll 4
        for (int m = 0; m < 64; ++m) {
            bf16x8 p0 = a0, p1 = a1;
            if (m < 63) {
                a0 = *reinterpret_cast<const bf16x8*>(sb + ((m + 1) * 16 + lr) * 64 + lk);
                a1 = *reinterpret_cast<const bf16x8*>(sb + ((m + 1) * 16 + lr) * 64 + 32 + lk);
            }
            f32x4 acc = {};
            acc = __builtin_amdgcn_mfma_f32_16x16x32_bf16(p0, b0, acc, 0, 0, 0);
            acc = __builtin_amdgcn_mfma_f32_16x16x32_bf16(p1, b1, acc, 0, 0, 0);
            *reinterpret_cast<f32x4*>(orow + m * 16) = acc;
        }
    }
}

extern "C" void kernel_launch(void* const* d_in, const int* in_sizes, int n_in,
                              void* d_out, int out_size, void* d_ws, size_t ws_size,
                              hipStream_t stream) {
    const float* state = (const float*)d_in[0];   // 1024 x 64
    const float* act   = (const float*)d_in[1];   // 64 x 32
    const float* core  = (const float*)d_in[2];   // 32 x 64 x 64
    float* out = (float*)d_out;                   // 64 x 1024 x 1024

    unsigned short* sb = (unsigned short*)d_ws;   // state bf16: 65536 (128 KB)
    unsigned short* wt = sb + 65536;              // Wt bf16:   262144 (512 KB)
    unsigned short* u  = wt + 262144;             // U bf16:    4194304 (8 MB)

    prep<<<64, 256, 0, stream>>>(state, act, core, sb, wt);
    gemm_u<<<256, 256, 0, stream>>>(sb, wt, u);
    gemm_out<<<1024, 256, 0, stream>>>(u, sb, out);
}

// Round 8
// 87.450 us; speedup vs baseline: 4.1321x; 4.1321x over previous
//
#include <hip/hip_runtime.h>
#include <hip/hip_bf16.h>

// Tucker: out[a,s,t] = sum_{f,e,g} act[a,f]*state[s,e]*core[f,e,g]*state[t,g]
// A=64, S=T=1024, E=G=64, F=32.
//
// R7 = R6 with the OOB fix: fused preamble must index state by s-WITHIN-a
// ((rb&15)*64 + ...), not the flat (a,s) out-row (R0 = rb*64, up to 65472 --
// 64x past sb's 1024 rows; read stale workspace -> absmax 0.259).
//  prep:  state->bf16 (sb) + Wt[a][g][e]=sum_f act*core (bf16), 256 blocks
//  gemm:  per block: compute own 64x64 U tile (MFMA, via 9KB LDS relayout),
//         then R3's t-sweep: out rows R0..R0+63, all 1024 t.

typedef __attribute__((ext_vector_type(8))) __bf16 bf16x8;
typedef __attribute__((ext_vector_type(4))) float f32x4;

static __device__ __forceinline__ unsigned short f2bf(float x) {
    union { float f; unsigned int u; } c; c.f = x;
    unsigned int lsb = (c.u >> 16) & 1u;
    c.u += 0x7fffu + lsb;               // round-to-nearest-even
    return (unsigned short)(c.u >> 16);
}

// ---- prep: fused state->bf16 conversion + Wt build (256 blocks) ----
__global__ __launch_bounds__(256) void prep(const float* __restrict__ state,
                                            const float* __restrict__ act,
                                            const float* __restrict__ core,
                                            unsigned short* __restrict__ sb,
                                            unsigned short* __restrict__ wt) {
    int bx = blockIdx.x;          // 256 blocks: a(64) x chunk(4)
    int a = bx >> 2, ch = bx & 3;
    int t = threadIdx.x;
    {   // state cvt: 16384 float4s, 64 per block (threads 0..63)
        if (t < 64) {
            int i = bx * 64 + t;
            float4 v = reinterpret_cast<const float4*>(state)[i];
            union { unsigned short u[4]; unsigned long long ull; } r;
            r.u[0] = f2bf(v.x); r.u[1] = f2bf(v.y); r.u[2] = f2bf(v.z); r.u[3] = f2bf(v.w);
            reinterpret_cast<unsigned long long*>(sb)[i] = r.ull;
        }
    }
    __shared__ float af[32];
    if (t < 32) af[t] = act[a * 32 + t];
    __syncthreads();
#pragma unroll
    for (int i = 0; i < 4; ++i) {
        int idx = ch * 1024 + i * 256 + t;   // 1024 (e,g) pairs per block
        int e = idx >> 6, g = idx & 63;
        float acc = 0.f;
#pragma unroll
        for (int f = 0; f < 32; ++f)
            acc += af[f] * core[(f * 64 + e) * 64 + g];
        wt[a * 4096 + g * 64 + e] = f2bf(acc);   // store transposed (g,e)
    }
}

// ---- gemm: fused U-tile + t-sweep ----
// Block owns 64 out rows (one a). Preamble: U[s][g] for its rows via MFMA
// (A = wt_a g-rows, B = sb s-rows), packed bf16 into LDS [64][72] to convert
// to B-frag layout. Sweep: identical to R3 (measured best).
__global__ __launch_bounds__(256) void gemm(const unsigned short* __restrict__ sb,
                                            const unsigned short* __restrict__ wt,
                                            float* __restrict__ out) {
    constexpr int UP = 72;                // LDS pitch in bf16: 144B rows, 16B-aligned
    __shared__ unsigned short uls[64 * UP];   // 9216 B

    int bx = blockIdx.x;                  // 1024 blocks
    int rb = (bx & 7) * 128 + (bx >> 3);  // XCD-chunked row-block (bijective)
    int wid = threadIdx.x >> 6, lane = threadIdx.x & 63;
    int lr = lane & 15, lk = (lane >> 4) * 8;
    int rr = (lane >> 4) * 4;
    size_t R0 = (size_t)rb * 64;          // first out row (flat (a,s))
    int a = rb >> 4;                      // 16 blocks per a
    int sloc = (rb & 15) * 64;            // s-within-a of first row  <-- R7 FIX

    // ---- preamble: U[s][g] = sum_e sb[sloc+s][e] * wta[g][e], s,g in [0,64) ----
    {
        const unsigned short* wta = wt + a * 4096;
        // B-frag: this wave's 16 s-rows (state rows sloc + wid*16 + 0..15)
        bf16x8 bs0 = *reinterpret_cast<const bf16x8*>(sb + (sloc + wid * 16 + lr) * 64 + lk);
        bf16x8 bs1 = *reinterpret_cast<const bf16x8*>(sb + (sloc + wid * 16 + lr) * 64 + 32 + lk);
        f32x4 uacc[4] = {};
#pragma unroll
        for (int mg = 0; mg < 4; ++mg) {  // A-frags: wt g-rows
            bf16x8 a0 = *reinterpret_cast<const bf16x8*>(wta + (mg * 16 + lr) * 64 + lk);
            bf16x8 a1 = *reinterpret_cast<const bf16x8*>(wta + (mg * 16 + lr) * 64 + 32 + lk);
            uacc[mg] = __builtin_amdgcn_mfma_f32_16x16x32_bf16(a0, bs0, uacc[mg], 0, 0, 0);
            uacc[mg] = __builtin_amdgcn_mfma_f32_16x16x32_bf16(a1, bs1, uacc[mg], 0, 0, 0);
        }
        // lane holds U[s = wid*16+lr][g = mg*16+rr+q], q=0..3 -> pack 8B to LDS
        unsigned short* ur = uls + (wid * 16 + lr) * UP;
#pragma unroll
        for (int mg = 0; mg < 4; ++mg) {
            union { unsigned short h[4]; unsigned long long ull; } pk;
#pragma unroll
            for (int q = 0; q < 4; ++q) pk.h[q] = f2bf(uacc[mg][q]);
            *reinterpret_cast<unsigned long long*>(ur + mg * 16 + rr) = pk.ull;
        }
    }
    __syncthreads();

    // B-frags for the sweep: this wave's 16 out-rows of U from LDS
    bf16x8 b0 = *reinterpret_cast<const bf16x8*>(uls + (wid * 16 + lr) * UP + lk);
    bf16x8 b1 = *reinterpret_cast<const bf16x8*>(uls + (wid * 16 + lr) * UP + 32 + lk);

    // ---- t-sweep (identical to R3) ----
    bf16x8 a0 = *reinterpret_cast<const bf16x8*>(sb + lr * 64 + lk);
    bf16x8 a1 = *reinterpret_cast<const bf16x8*>(sb + lr * 64 + 32 + lk);
    float* orow = out + (R0 + wid * 16 + lr) * 1024 + rr;

#pragma unroll 4
    for (int m = 0; m < 64; ++m) {
        bf16x8 p0 = a0, p1 = a1;
        if (m < 63) {
            a0 = *reinterpret_cast<const bf16x8*>(sb + ((m + 1) * 16 + lr) * 64 + lk);
            a1 = *reinterpret_cast<const bf16x8*>(sb + ((m + 1) * 16 + lr) * 64 + 32 + lk);
        }
        f32x4 acc = {};
        acc = __builtin_amdgcn_mfma_f32_16x16x32_bf16(p0, b0, acc, 0, 0, 0);
        acc = __builtin_amdgcn_mfma_f32_16x16x32_bf16(p1, b1, acc, 0, 0, 0);
        // lane holds out[R0+wid*16+lr][m*16 + rr + q], q=0..3 -> one 16B store
        *reinterpret_cast<f32x4*>(orow + m * 16) = acc;
    }
}

extern "C" void kernel_launch(void* const* d_in, const int* in_sizes, int n_in,
                              void* d_out, int out_size, void* d_ws, size_t ws_size,
                              hipStream_t stream) {
    const float* state = (const float*)d_in[0];   // 1024 x 64
    const float* act   = (const float*)d_in[1];   // 64 x 32
    const float* core  = (const float*)d_in[2];   // 32 x 64 x 64
    float* out = (float*)d_out;                   // 64 x 1024 x 1024

    unsigned short* sb = (unsigned short*)d_ws;   // state bf16: 65536 (128 KB)
    unsigned short* wt = sb + 65536;              // Wt bf16:   262144 (512 KB)

    prep<<<256, 256, 0, stream>>>(state, act, core, sb, wt);
    gemm<<<1024, 256, 0, stream>>>(sb, wt, out);
}